// Round 10
// baseline (441.816 us; speedup 1.0000x reference)
//
#include <hip/hip_runtime.h>
#include <hip/hip_bf16.h>

#define UNITS 512
#define SEQ   4096
#define BATCH 32

typedef __attribute__((ext_vector_type(8))) __bf16 bf16x8;
typedef __attribute__((ext_vector_type(4))) float  f32x4;

// LDS swizzle for 64B-stride rows: phys = l ^ (((l>>6)&7)<<4).
__device__ __forceinline__ int swzB(int l) { return l ^ (((l >> 6) & 7) << 4); }

#define MFMA(A, B, C) __builtin_amdgcn_mfma_f32_16x16x32_bf16(A, B, C, 0, 0, 0)
#define GLL(SRC, DST) __builtin_amdgcn_global_load_lds( \
    (const __attribute__((address_space(1))) void*)(SRC), \
    (__attribute__((address_space(3))) void*)(DST), 16, 0, 0)
#define PK8(X, Y) ({ bf16x8 _o; \
    _o[0]=(__bf16)(X).x; _o[1]=(__bf16)(X).y; _o[2]=(__bf16)(X).z; _o[3]=(__bf16)(X).w; \
    _o[4]=(__bf16)(Y).x; _o[5]=(__bf16)(Y).y; _o[6]=(__bf16)(Y).z; _o[7]=(__bf16)(Y).w; _o; })
#define FENCE() asm volatile("" ::: "memory")

// ---------------- K0: Uw [k][n] f32 -> UwTt: 64 tiles (kstep 0..15, q 0..3) ------
// Tile (kstep,q) = [128 n][32 k] bf16 = 8KB, 64B rows, PRE-SWIZZLED (swzB).
__global__ void k_bprep(const float* __restrict__ Uw, __bf16* __restrict__ UwTt) {
    const int kstep = blockIdx.x;        // 0..15
    const int q     = blockIdx.y;        // 0..3
    const int t     = threadIdx.x;       // 0..255
    const int nl    = t & 127;
    const int h     = t >> 7;            // k-half (16 k each)
    const int n     = q * 128 + nl;
    const int k0    = kstep * 32 + h * 16;
    bf16x8 o0, o1;
#pragma unroll
    for (int j = 0; j < 8; j++) {
        o0[j] = (__bf16)Uw[(size_t)(k0 + j) * UNITS + n];
        o1[j] = (__bf16)Uw[(size_t)(k0 + 8 + j) * UNITS + n];
    }
    char* base = (char*)UwTt + (size_t)(kstep * 4 + q) * 8192;
    *(bf16x8*)(base + swzB(nl * 64 + h * 32))      = o0;
    *(bf16x8*)(base + swzB(nl * 64 + h * 32 + 16)) = o1;
}

// ---------------- KA: ws_Ws[b][v] = s_prev[b,:] @ Ww[:,v] + Wb[v] + Ub[v] --------
__global__ void k_wsrow(const float* __restrict__ s_prev, const float* __restrict__ Ww,
                        const float* __restrict__ Wb, const float* __restrict__ Ub,
                        float* __restrict__ ws_Ws) {
    __shared__ float sp[UNITS];
    int b = blockIdx.x, t = threadIdx.x;
    sp[t] = s_prev[b * UNITS + t];
    sp[t + 256] = s_prev[b * UNITS + t + 256];
    __syncthreads();
    float a0 = Wb[t] + Ub[t];
    float a1 = Wb[t + 256] + Ub[t + 256];
#pragma unroll 8
    for (int u = 0; u < UNITS; u++) {
        float s = sp[u];
        a0 += s * Ww[u * UNITS + t];
        a1 += s * Ww[u * UNITS + t + 256];
    }
    ws_Ws[b * UNITS + t] = a0;
    ws_Ws[b * UNITS + t + 256] = a1;
}

// ---------------- KB: fused  tanh(Ws + hidden@Uw) @ Vw  ->  logit partials -------
// A-DIRECT: A fragments loaded straight from global (f32 -> cvt -> pack in regs),
// 2 steps ahead, parity-buffered. No A LDS, no A in barrier dependence.
// B: pre-swizzled global_load_lds double-buffer; ONE barrier per step with
// counted vmcnt(8) guarding only the B-gll. 128x128 tile, BK=32, 256 thr.
#define BM 128
#define BN 128
#define BK 32
#define NSTEP (UNITS / BK)

__launch_bounds__(256, 3)
__global__ void k_logits(const float* __restrict__ hidden, const __bf16* __restrict__ UwTt,
                         const float* __restrict__ wsu, const float* __restrict__ Vw,
                         float* __restrict__ lpart) {
    __shared__ __bf16 Bb[2][BN * BK];   // 8KB per buf, pre-swizzled source
    __shared__ float  lred[BM][2];      // 1KB -> 17KB total

    const int t = threadIdx.x;
    const int lane = t & 63, wv = t >> 6;
    const int wm = wv >> 1, wn = wv & 1;          // 2 x 2 wave grid, 64x64/wave
    const int l15 = lane & 15, l4 = lane >> 4;

    const int id = blockIdx.x;                    // 0..4095
    const int gx = (id >> 3) & 3;
    const int mt = ((id >> 5) << 3) | (id & 7);   // 0..1023  (gx blocks share XCD)
    const int m0 = mt * BM;
    const int b  = m0 >> 12;

    f32x4 acc[4][4];
#pragma unroll
    for (int i = 0; i < 4; i++)
#pragma unroll
        for (int j = 0; j < 4; j++) acc[i][j] = (f32x4){0.f, 0.f, 0.f, 0.f};

    // A fragment base pointers: frag fi -> row m0+wm*64+fi*16+l15, k-col l4*8
    const float* aF[4];
#pragma unroll
    for (int f = 0; f < 4; f++)
        aF[f] = hidden + (size_t)(m0 + wm * 64 + f * 16 + l15) * UNITS + l4 * 8;

    int boffR[4];
#pragma unroll
    for (int f = 0; f < 4; f++)
        boffR[f] = swzB((wn * 64 + f * 16 + l15) * 64 + l4 * 16);

    const char* bglBase = (const char*)UwTt + (size_t)gx * 8192 + wv * 2048 + lane * 16;

    float4 afl[2][8];     // parity-indexed f32 A staging (all indices fold constant)
    bf16x8 apk[4];        // packed bf16 A for the current step

    // ---- prologue: gll(0); A(0); A(1); sync; pack A(0) ----
    GLL(bglBase,        (char*)Bb[0] + wv * 2048);
    GLL(bglBase + 1024, (char*)Bb[0] + wv * 2048 + 1024);
    FENCE();
#pragma unroll
    for (int f = 0; f < 4; f++) {
        afl[0][2 * f]     = *(const float4*)(aF[f]);
        afl[0][2 * f + 1] = *(const float4*)(aF[f] + 4);
    }
    FENCE();
#pragma unroll
    for (int f = 0; f < 4; f++) {
        afl[1][2 * f]     = *(const float4*)(aF[f] + BK);
        afl[1][2 * f + 1] = *(const float4*)(aF[f] + BK + 4);
    }
    asm volatile("s_waitcnt vmcnt(16)" ::: "memory");   // gll(0) landed; 16 A in flight
    __builtin_amdgcn_s_barrier();
#pragma unroll
    for (int f = 0; f < 4; f++)
        apk[f] = PK8(afl[0][2 * f], afl[0][2 * f + 1]); // compiler auto-waits A(0)

#pragma unroll
    for (int s = 0; s < NSTEP; ++s) {
        const int cur = s & 1;
        // B fragment reads for step s
        bf16x8 bq[4];
#pragma unroll
        for (int fj = 0; fj < 4; fj++)
            bq[fj] = *(const bf16x8*)((const char*)Bb[cur] + boffR[fj]);
        // issue next B tile (cur^1 free since barrier at end of s-1)
        if (s + 1 < NSTEP) {
            const char* bs = bglBase + (size_t)(s + 1) * 32768;
            GLL(bs,        (char*)Bb[cur ^ 1] + wv * 2048);
            GLL(bs + 1024, (char*)Bb[cur ^ 1] + wv * 2048 + 1024);
        }
        FENCE();
        // issue A(s+2) into the parity slot freed by A(s)
        if (s + 2 < NSTEP) {
#pragma unroll
            for (int f = 0; f < 4; f++) {
                afl[cur][2 * f]     = *(const float4*)(aF[f] + (s + 2) * BK);
                afl[cur][2 * f + 1] = *(const float4*)(aF[f] + (s + 2) * BK + 4);
            }
        }
        asm volatile("s_waitcnt lgkmcnt(0)" ::: "memory");
        __builtin_amdgcn_sched_barrier(0);
#pragma unroll
        for (int fi = 0; fi < 4; fi++)
#pragma unroll
            for (int fj = 0; fj < 4; fj++)
                acc[fi][fj] = MFMA(apk[fi], bq[fj], acc[fi][fj]);
        // pack A(s+1) (loads issued at step s-1; ~1.5 steps of latency cover)
        if (s + 1 < NSTEP) {
            if (s + 2 < NSTEP) asm volatile("s_waitcnt vmcnt(10)" ::: "memory");
            else               asm volatile("s_waitcnt vmcnt(2)"  ::: "memory");
#pragma unroll
            for (int f = 0; f < 4; f++)
                apk[f] = PK8(afl[cur ^ 1][2 * f], afl[cur ^ 1][2 * f + 1]);
            // own gll(s+1) landed before barrier => after barrier all waves' landed
            if (s + 2 < NSTEP) asm volatile("s_waitcnt vmcnt(8)" ::: "memory");
            else               asm volatile("s_waitcnt vmcnt(0)" ::: "memory");
            __builtin_amdgcn_s_barrier();
        }
    }

    // epilogue: tanh(acc + Ws+Ub) * Vw, reduce over this block's 128 cols
    float wsub[4], vww[4];
#pragma unroll
    for (int fj = 0; fj < 4; fj++) {
        int n = gx * BN + wn * 64 + fj * 16 + l15;
        wsub[fj] = wsu[b * UNITS + n];
        vww[fj]  = Vw[n];
    }
#pragma unroll
    for (int fi = 0; fi < 4; fi++) {
#pragma unroll
        for (int r = 0; r < 4; r++) {
            float p = 0.f;
#pragma unroll
            for (int fj = 0; fj < 4; fj++) {
                float x = acc[fi][fj][r] + wsub[fj];
                float e = __expf(2.f * x);
                p += vww[fj] * (1.f - 2.f / (e + 1.f));   // tanh(x)
            }
#pragma unroll
            for (int off = 1; off < 16; off <<= 1) p += __shfl_xor(p, off);
            if (l15 == 0) lred[wm * 64 + fi * 16 + l4 * 4 + r][wn] = p;
        }
    }
    __syncthreads();
    if (t < BM) {
        lpart[(size_t)(m0 + t) * 4 + gx] = lred[t][0] + lred[t][1];
    }
}

// ---------------- KC: softmax over seq axis, write weights ----------------------
__global__ void k_softmax(const float* __restrict__ lpart, float* __restrict__ wout) {
    __shared__ float ebuf[SEQ];
    __shared__ float red[8];
    int b = blockIdx.x, t = threadIdx.x;
    int lane = t & 63, wv = t >> 6;
    float m = -1e30f;
#pragma unroll
    for (int i = 0; i < 16; i++) {
        int s = t + i * 256;
        size_t idx = ((size_t)b * SEQ + s) * 4;
        float l = (lpart[idx] + lpart[idx + 1]) + (lpart[idx + 2] + lpart[idx + 3]);
        ebuf[s] = l;
        m = fmaxf(m, l);
    }
#pragma unroll
    for (int off = 32; off >= 1; off >>= 1) m = fmaxf(m, __shfl_xor(m, off));
    if (lane == 0) red[wv] = m;
    __syncthreads();
    m = fmaxf(fmaxf(red[0], red[1]), fmaxf(red[2], red[3]));
    float zs = 0.f;
#pragma unroll
    for (int i = 0; i < 16; i++) {
        int s = t + i * 256;
        float e = __expf(ebuf[s] - m);
        ebuf[s] = e;
        zs += e;
    }
#pragma unroll
    for (int off = 32; off >= 1; off >>= 1) zs += __shfl_xor(zs, off);
    __syncthreads();
    if (lane == 0) red[wv] = zs;
    __syncthreads();
    float inv = 1.f / (red[0] + red[1] + red[2] + red[3]);
#pragma unroll
    for (int i = 0; i < 16; i++) {
        int s = t + i * 256;
        wout[(size_t)b * SEQ + s] = ebuf[s] * inv;
    }
}

// ---------------- KD: context partials over 128-seq chunks ----------------------
__global__ void k_ctxpart(const float* __restrict__ hidden, const float* __restrict__ wout,
                          float* __restrict__ part) {
    int b = blockIdx.y, c = blockIdx.x, t = threadIdx.x;
    const float* w = wout + (size_t)b * SEQ + c * 128;
    const float* h = hidden + ((size_t)b * SEQ + c * 128) * UNITS;
    float2 acc = make_float2(0.f, 0.f);
#pragma unroll 4
    for (int s = 0; s < 128; s++) {
        float ww = w[s];
        float2 v = ((const float2*)(h + (size_t)s * UNITS))[t];
        acc.x += ww * v.x;
        acc.y += ww * v.y;
    }
    ((float2*)(part + ((size_t)(b * 32 + c)) * UNITS))[t] = acc;
}

// ---------------- KE: reduce partials -> context --------------------------------
__global__ void k_ctxreduce(const float* __restrict__ part, float* __restrict__ ctx) {
    int b = blockIdx.x, t = threadIdx.x;
    float s = 0.f;
#pragma unroll
    for (int c = 0; c < 32; c++) s += part[((size_t)(b * 32 + c)) * UNITS + t];
    ctx[(size_t)b * UNITS + t] = s;
}

extern "C" void kernel_launch(void* const* d_in, const int* in_sizes, int n_in,
                              void* d_out, int out_size, void* d_ws, size_t ws_size,
                              hipStream_t stream) {
    const float* s_prev = (const float*)d_in[0];
    const float* hidden = (const float*)d_in[1];
    const float* Ww     = (const float*)d_in[2];
    const float* Wb     = (const float*)d_in[3];
    const float* Uw     = (const float*)d_in[4];
    const float* Ub     = (const float*)d_in[5];
    const float* Vw     = (const float*)d_in[6];
    // d_in[7] = Vb: constant shift, cancels in softmax.

    float* out  = (float*)d_out;
    float* ctx  = out;                    // [32, 512]
    float* wout = out + BATCH * UNITS;    // [32, 4096, 1]

    float* wsf   = (float*)d_ws;
    float* ws_Ws = wsf;                                  // 16384 f32
    float* ws_lp = ws_Ws + BATCH * UNITS;                // 524288 f32 (4 quarters)
    float* ws_cp = ws_lp + (size_t)BATCH * SEQ * 4;      // 524288 f32
    __bf16* UwTt = (__bf16*)(ws_cp + (size_t)BATCH * 32 * UNITS);  // 512 KB bf16

    k_bprep<<<dim3(16, 4), dim3(256), 0, stream>>>(Uw, UwTt);
    k_wsrow<<<dim3(32), dim3(256), 0, stream>>>(s_prev, Ww, Wb, Ub, ws_Ws);
    k_logits<<<dim3(4096), dim3(256), 0, stream>>>(hidden, UwTt, ws_Ws, Vw, ws_lp);
    k_softmax<<<dim3(32), dim3(256), 0, stream>>>(ws_lp, wout);
    k_ctxpart<<<dim3(32, 32), dim3(256), 0, stream>>>(hidden, wout, ws_cp);
    k_ctxreduce<<<dim3(32), dim3(512), 0, stream>>>(ws_cp, ctx);
}